// Round 12
// baseline (365.619 us; speedup 1.0000x reference)
//
#include <hip/hip_runtime.h>

// GAT 2-layer forward on MI355X.
// Round 22: schedule-level fusion (the within-kernel levers are exhausted:
// agg MLP optimum r11/r16/r20; residency null r17; LDS traffic done r19;
// build restructures r12/r13/r14/r21 mixed-to-null; totals 323/326/332 =
// noise +-4us). Accounting never closed: ~225-250us of kernel time vs 326
// measured, all serialized.
//  (a) rp_sort reverted to r15/r19 single-bucket (r21 half-split: -5us worse).
//  (b) scatter_gemm1: dual-role kernel. Blocks [0,NWG) = chunk scatter
//      (36KB LDS union), blocks [NWG,NWG+gN) = gemm1f (16.6KB of the same
//      union). gemm1f is independent of the CSR chain -> its ~20-45us hides
//      inside the scatter's memory/sync stalls. Scatter blocks first so
//      rp_sort's dependency is not delayed.
//  (c) bucket_hist_scan: bucket_scan folded in via last-block-done atomic
//      (one device atomic/block; last block runs the 512-wide scan).
// 9 enqueues -> 6. agg1_attn/agg2_gemm byte-identical r15; gemm1f logic r19.

#define DEVFN __device__ __forceinline__
#define CB_SHIFT 8
#define CB_SZ 256
#define SC_CHUNK 4096
#define NBMAX 512    // max buckets supported (N <= 131072)
#define STASH 12288  // bucket stash entries (mean ~8.5k)

DEVFN unsigned short f2h(float f) {
  _Float16 h = (_Float16)f;
  unsigned short u;
  __builtin_memcpy(&u, &h, 2);
  return u;
}
DEVFN float h2f(unsigned short u) {
  _Float16 h;
  __builtin_memcpy(&h, &u, 2);
  return (float)h;
}

DEVFN float lrelu(float e) { return e > 0.f ? e : 0.2f * e; }

DEVFN void acc8(float* acc, float x, uint4 u) {
  acc[0] = fmaf(x, h2f(u.x & 0xffff), acc[0]);
  acc[1] = fmaf(x, h2f(u.x >> 16),    acc[1]);
  acc[2] = fmaf(x, h2f(u.y & 0xffff), acc[2]);
  acc[3] = fmaf(x, h2f(u.y >> 16),    acc[3]);
  acc[4] = fmaf(x, h2f(u.z & 0xffff), acc[4]);
  acc[5] = fmaf(x, h2f(u.z >> 16),    acc[5]);
  acc[6] = fmaf(x, h2f(u.w & 0xffff), acc[6]);
  acc[7] = fmaf(x, h2f(u.w >> 16),    acc[7]);
}

DEVFN void read_edge(const long long* eg64, const int* eg32, int is64, int E,
                     int i, int& s, int& d) {
  if (i >= E) { s = d = i - E; return; }
  if (is64) { s = (int)eg64[i]; d = (int)eg64[E + i]; }
  else      { s = eg32[i];      d = eg32[E + i]; }
}

// block-uniform edge dtype detection: EVERY wave samples the same 64 in-range
// indices (int64 data => high words all zero; int32 data => random src values).
DEVFN int detect64(const int* eg32, int E, int i0, int t) {
  int base = i0;
  if (base > E - 64) base = E - 64;
  if (base < 0) base = 0;
  int i = base + (t & 63);
  unsigned long long m = __ballot((i < E) && (eg32[2 * i + 1] != 0));
  return m == 0ull;
}

// ---- CSR build stage 1+2 fused: bucket histogram + last-block scan ---------
__global__ __launch_bounds__(256) void bucket_hist_scan(
    const long long* eg64, const int* eg32, int E, int N, int NB2,
    int* __restrict__ bhist, int* __restrict__ bflag,
    int* __restrict__ bscan, int* __restrict__ gcur) {
  __shared__ int lh[NBMAX];
  __shared__ int sbuf[2][NBMAX];
  __shared__ int lastblk;
  int t = threadIdx.x;
  lh[t] = 0; lh[t + 256] = 0;
  int is64 = detect64(eg32, E, 0, t);
  __syncthreads();
  int EN = E + N;
  int step = (int)gridDim.x * 1024;
  for (int base = (int)blockIdx.x * 1024; base < EN; base += step) {
#pragma unroll
    for (int k = 0; k < 4; k++) {
      int i = base + k * 256 + t;
      if (i < EN) {
        int d;
        if (i >= E) d = i - E;
        else d = is64 ? (int)eg64[E + i] : eg32[E + i];
        atomicAdd(&lh[d >> CB_SHIFT], 1);
      }
    }
  }
  __syncthreads();
  if (t < NB2 && lh[t]) atomicAdd(&bhist[t], lh[t]);
  int t2 = t + 256;
  if (t2 < NB2 && lh[t2]) atomicAdd(&bhist[t2], lh[t2]);
  // last-block-done: one device atomic per block; loser blocks exit.
  __threadfence();
  __syncthreads();
  if (t == 0) lastblk = (atomicAdd(bflag, 1) == (int)gridDim.x - 1);
  __syncthreads();
  if (!lastblk) return;
  __threadfence();  // see all blocks' bhist contributions
  int v0 = (t < NB2) ? bhist[t] : 0;
  int v1 = (t2 < NB2) ? bhist[t2] : 0;
  sbuf[0][t] = v0; sbuf[0][t + 256] = v1;
  __syncthreads();
  int pin = 0;
  for (int off = 1; off < NBMAX; off <<= 1) {
    int nv0 = sbuf[pin][t] + (t >= off ? sbuf[pin][t - off] : 0);
    int nv1 = sbuf[pin][t + 256] + sbuf[pin][t + 256 - off];
    __syncthreads();
    sbuf[1 - pin][t] = nv0; sbuf[1 - pin][t + 256] = nv1;
    pin ^= 1;
    __syncthreads();
  }
  int e0 = sbuf[pin][t] - v0;
  int e1 = sbuf[pin][t + 256] - v1;
  if (t < NB2) { bscan[t] = e0; gcur[t] = e0; }
  if (t2 < NB2) { bscan[t2] = e1; gcur[t2] = e1; }
  if (t == 0) bscan[NB2] = EN;
}

// ---- dual-role: chunk scatter (blocks < NWG) | gemm1f (blocks >= NWG) ------
union SMem {
  struct {
    int lh[NBMAX]; int lscan[NBMAX]; int lpos[NBMAX]; int gbase[NBMAX];
    int sbuf[2][NBMAX]; int payl[SC_CHUNK]; unsigned short bktid[SC_CHUNK];
  } sc;  // 36 KB
  struct {
    float Wl[128 * 32]; float Asl[32]; float Adl[32];
  } g1;  // 16.6 KB
};

__global__ __launch_bounds__(256) void scatter_gemm1(
    const long long* eg64, const int* eg32, int E, int N, int NB2, int NWG,
    int* __restrict__ gcur, int* __restrict__ tmp,
    const float* __restrict__ X, const float* __restrict__ W,
    const float* __restrict__ att_s, const float* __restrict__ att_d,
    uint4* __restrict__ h1h, float* __restrict__ as1,
    float* __restrict__ ad1) {
  __shared__ SMem sm;
  int t = threadIdx.x;
  if ((int)blockIdx.x < NWG) {
    // ---------------- scatter role (r15 chunk_scatter_sorted) --------------
    int i0 = (int)blockIdx.x * SC_CHUNK;
    int is64 = detect64(eg32, E, i0, t);
    sm.sc.lh[t] = 0; sm.sc.lh[t + 256] = 0;
    __syncthreads();
    int EN = E + N;
    int i1 = i0 + SC_CHUNK; if (i1 > EN) i1 = EN;
    int total = i1 - i0;
    int es[16], ed[16];
#pragma unroll
    for (int bb = 0; bb < 4; bb++) {
#pragma unroll
      for (int k = 0; k < 4; k++) {
        int idx = bb * 4 + k;
        int i = i0 + bb * 1024 + k * 256 + t;
        int s = 0, d = -1;
        if (i < i1) read_edge(eg64, eg32, is64, E, i, s, d);
        es[idx] = s; ed[idx] = d;
      }
    }
#pragma unroll
    for (int j = 0; j < 16; j++)
      if (ed[j] >= 0) atomicAdd(&sm.sc.lh[ed[j] >> CB_SHIFT], 1);
    __syncthreads();
    sm.sc.sbuf[0][t] = sm.sc.lh[t]; sm.sc.sbuf[0][t + 256] = sm.sc.lh[t + 256];
    __syncthreads();
    int pin = 0;
    for (int off = 1; off < NBMAX; off <<= 1) {
      int nv0 = sm.sc.sbuf[pin][t] + (t >= off ? sm.sc.sbuf[pin][t - off] : 0);
      int nv1 = sm.sc.sbuf[pin][t + 256] + sm.sc.sbuf[pin][t + 256 - off];
      __syncthreads();
      sm.sc.sbuf[1 - pin][t] = nv0; sm.sc.sbuf[1 - pin][t + 256] = nv1;
      pin ^= 1;
      __syncthreads();
    }
    sm.sc.lscan[t] = sm.sc.sbuf[pin][t] - sm.sc.lh[t];
    sm.sc.lscan[t + 256] = sm.sc.sbuf[pin][t + 256] - sm.sc.lh[t + 256];
    sm.sc.lpos[t] = sm.sc.lscan[t]; sm.sc.lpos[t + 256] = sm.sc.lscan[t + 256];
    if (t < NB2 && sm.sc.lh[t])
      sm.sc.gbase[t] = atomicAdd(&gcur[t], sm.sc.lh[t]);
    int t2 = t + 256;
    if (t2 < NB2 && sm.sc.lh[t2])
      sm.sc.gbase[t2] = atomicAdd(&gcur[t2], sm.sc.lh[t2]);
    __syncthreads();
#pragma unroll
    for (int j = 0; j < 16; j++) {
      if (ed[j] >= 0) {
        int b = ed[j] >> CB_SHIFT;
        int sl = atomicAdd(&sm.sc.lpos[b], 1);
        sm.sc.payl[sl] = (es[j] << CB_SHIFT) | (ed[j] & (CB_SZ - 1));
        sm.sc.bktid[sl] = (unsigned short)b;
      }
    }
    __syncthreads();
    for (int j = t; j < total; j += 256) {
      int b = sm.sc.bktid[j];
      tmp[sm.sc.gbase[b] + (j - sm.sc.lscan[b])] = sm.sc.payl[j];
    }
  } else {
    // ---------------- gemm1f role (r19 ch-split x node-pair) ---------------
    for (int i = t; i < 1024; i += 256)
      ((float4*)sm.g1.Wl)[i] = ((const float4*)W)[i];
    if (t < 32) { sm.g1.Asl[t] = att_s[t]; sm.g1.Adl[t] = att_d[t]; }
    __syncthreads();
    int g = t >> 2, j = t & 3;
    int n0 = ((int)blockIdx.x - NWG) * 128 + g * 2;
    int n1 = n0 + 1;
    bool v0 = n0 < N, v1 = n1 < N;
    const float4* X40 = (const float4*)(X + (size_t)n0 * 128);
    const float4* X41 = (const float4*)(X + (size_t)n1 * 128);
    float a0[8], a1[8];
#pragma unroll
    for (int c = 0; c < 8; c++) { a0[c] = 0.f; a1[c] = 0.f; }
    float4 z4 = {0.f, 0.f, 0.f, 0.f};
    for (int k4 = 0; k4 < 32; k4++) {
      float4 x0 = v0 ? X40[k4] : z4;
      float4 x1 = v1 ? X41[k4] : z4;
      const float4* w4 = (const float4*)(sm.g1.Wl + k4 * 128);
      int cb = j * 2;
#pragma unroll
      for (int kr = 0; kr < 4; kr++) {
        float4 wa = w4[kr * 8 + cb];
        float4 wb = w4[kr * 8 + cb + 1];
        float xc0 = kr == 0 ? x0.x : kr == 1 ? x0.y : kr == 2 ? x0.z : x0.w;
        float xc1 = kr == 0 ? x1.x : kr == 1 ? x1.y : kr == 2 ? x1.z : x1.w;
        a0[0] = fmaf(xc0, wa.x, a0[0]); a0[1] = fmaf(xc0, wa.y, a0[1]);
        a0[2] = fmaf(xc0, wa.z, a0[2]); a0[3] = fmaf(xc0, wa.w, a0[3]);
        a0[4] = fmaf(xc0, wb.x, a0[4]); a0[5] = fmaf(xc0, wb.y, a0[5]);
        a0[6] = fmaf(xc0, wb.z, a0[6]); a0[7] = fmaf(xc0, wb.w, a0[7]);
        a1[0] = fmaf(xc1, wa.x, a1[0]); a1[1] = fmaf(xc1, wa.y, a1[1]);
        a1[2] = fmaf(xc1, wa.z, a1[2]); a1[3] = fmaf(xc1, wa.w, a1[3]);
        a1[4] = fmaf(xc1, wb.x, a1[4]); a1[5] = fmaf(xc1, wb.y, a1[5]);
        a1[6] = fmaf(xc1, wb.z, a1[6]); a1[7] = fmaf(xc1, wb.w, a1[7]);
      }
    }
    int ch0 = j * 8;
    float ps0 = 0.f, pd0 = 0.f, ps1 = 0.f, pd1 = 0.f;
#pragma unroll
    for (int c = 0; c < 8; c++) {
      ps0 = fmaf(a0[c], sm.g1.Asl[ch0 + c], ps0);
      pd0 = fmaf(a0[c], sm.g1.Adl[ch0 + c], pd0);
      ps1 = fmaf(a1[c], sm.g1.Asl[ch0 + c], ps1);
      pd1 = fmaf(a1[c], sm.g1.Adl[ch0 + c], pd1);
    }
    ps0 += __shfl_xor(ps0, 1); pd0 += __shfl_xor(pd0, 1);
    ps1 += __shfl_xor(ps1, 1); pd1 += __shfl_xor(pd1, 1);
    float qs0 = __shfl_xor(ps0, 2), qd0 = __shfl_xor(pd0, 2);
    float qs1 = __shfl_xor(ps1, 2), qd1 = __shfl_xor(pd1, 2);
    if (j == 0) {
      if (v0) {
        as1[n0 * 2] = ps0; as1[n0 * 2 + 1] = qs0;
        ad1[n0 * 2] = pd0; ad1[n0 * 2 + 1] = qd0;
      }
      if (v1) {
        as1[n1 * 2] = ps1; as1[n1 * 2 + 1] = qs1;
        ad1[n1 * 2] = pd1; ad1[n1 * 2 + 1] = qd1;
      }
    }
    if (v0) {
      uint4 u;
      u.x = (unsigned)f2h(a0[0]) | ((unsigned)f2h(a0[1]) << 16);
      u.y = (unsigned)f2h(a0[2]) | ((unsigned)f2h(a0[3]) << 16);
      u.z = (unsigned)f2h(a0[4]) | ((unsigned)f2h(a0[5]) << 16);
      u.w = (unsigned)f2h(a0[6]) | ((unsigned)f2h(a0[7]) << 16);
      h1h[(size_t)n0 * 4 + j] = u;
    }
    if (v1) {
      uint4 u;
      u.x = (unsigned)f2h(a1[0]) | ((unsigned)f2h(a1[1]) << 16);
      u.y = (unsigned)f2h(a1[2]) | ((unsigned)f2h(a1[3]) << 16);
      u.z = (unsigned)f2h(a1[4]) | ((unsigned)f2h(a1[5]) << 16);
      u.w = (unsigned)f2h(a1[6]) | ((unsigned)f2h(a1[7]) << 16);
      h1h[(size_t)n1 * 4 + j] = u;
    }
  }
}

// stage 4: per-bucket (256 nodes) node counts + in-LDS scan -> rp; scatter
// tmp -> csr. LDS stash avoids the global re-read in pass 2. (r15 form.)
__global__ __launch_bounds__(256) void bucket_rp_sort(const int* __restrict__ bscan,
                                                      const int* __restrict__ tmp,
                                                      int* __restrict__ rp,
                                                      int* __restrict__ csr,
                                                      int N, int EN) {
  __shared__ int lc[CB_SZ];
  __shared__ int ps[256];
  __shared__ int lcur[CB_SZ];
  __shared__ int stash[STASH];
  int b = blockIdx.x, t = threadIdx.x;
  lc[t] = 0;
  __syncthreads();
  int w0 = bscan[b];
  int w1 = bscan[b + 1];
  int cnt = w1 - w0;
  bool fit = (cnt <= STASH);
  int p = w0 + t;
  for (; p + 768 < w1; p += 1024) {
    int e0 = tmp[p], e1 = tmp[p + 256], e2 = tmp[p + 512], e3 = tmp[p + 768];
    if (fit) {
      stash[p - w0] = e0; stash[p - w0 + 256] = e1;
      stash[p - w0 + 512] = e2; stash[p - w0 + 768] = e3;
    }
    atomicAdd(&lc[e0 & (CB_SZ - 1)], 1);
    atomicAdd(&lc[e1 & (CB_SZ - 1)], 1);
    atomicAdd(&lc[e2 & (CB_SZ - 1)], 1);
    atomicAdd(&lc[e3 & (CB_SZ - 1)], 1);
  }
  if (p < w1) {
    bool v1 = p + 256 < w1, v2 = p + 512 < w1;
    int q1 = v1 ? p + 256 : p;
    int q2 = v2 ? p + 512 : p;
    int e0 = tmp[p], e1 = tmp[q1], e2 = tmp[q2];
    if (fit) {
      stash[p - w0] = e0;
      if (v1) stash[q1 - w0] = e1;
      if (v2) stash[q2 - w0] = e2;
    }
    atomicAdd(&lc[e0 & (CB_SZ - 1)], 1);
    if (v1) atomicAdd(&lc[e1 & (CB_SZ - 1)], 1);
    if (v2) atomicAdd(&lc[e2 & (CB_SZ - 1)], 1);
  }
  __syncthreads();
  int a = lc[t];
  ps[t] = a;
  __syncthreads();
  for (int off = 1; off < 256; off <<= 1) {
    int v = ps[t];
    int u = (t >= off) ? ps[t - off] : 0;
    __syncthreads();
    ps[t] = v + u;
    __syncthreads();
  }
  int base = w0 + ps[t] - a;  // exclusive prefix within bucket
  lcur[t] = base;
  int n0 = b * CB_SZ;
  if (n0 + t < N) rp[n0 + t] = base;
  if (b == (int)gridDim.x - 1 && t == 0) rp[N] = EN;
  __syncthreads();
  if (fit) {
    for (int j = t; j < cnt; j += 256) {
      int e = stash[j];
      int pos = atomicAdd(&lcur[e & (CB_SZ - 1)], 1);
      csr[pos] = e >> CB_SHIFT;
    }
  } else {
    for (int q = w0 + t; q < w1; q += 256) {
      int e = tmp[q];
      int pos = atomicAdd(&lcur[e & (CB_SZ - 1)], 1);
      csr[pos] = e >> CB_SHIFT;
    }
  }
}

// ------- fused agg1 (split-K=4, shfl) + x1 fp16 pack + attn2 dots -----------
// block = 16 nodes x 16 threads; r=(half 0-3, cq 0-3).
// gemm2 folded out via linearity: dots with va=W2*att_src2, vb=W2*att_dst2.
__global__ __launch_bounds__(256, 8) void agg1_attn(
    const int* __restrict__ rp, const int* __restrict__ csr,
    const float* __restrict__ as, const float* __restrict__ ad,
    const uint4* __restrict__ h1h, const float* __restrict__ b1,
    const float* __restrict__ W2, const float* __restrict__ as2w,
    const float* __restrict__ ad2w, uint4* __restrict__ x1h,
    float* __restrict__ as2, float* __restrict__ ad2, int N) {
  __shared__ float val[32], vbl[32];
  int t = threadIdx.x;
  if (t < 32) {
    float a = 0.f, b = 0.f;
    for (int c = 0; c < 40; c++) {
      float w = W2[t * 40 + c];
      a = fmaf(w, as2w[c], a);
      b = fmaf(w, ad2w[c], b);
    }
    val[t] = a; vbl[t] = b;
  }
  __syncthreads();
  int nl = t >> 4, r = t & 15;
  int half = r >> 2, cq = r & 3;
  int h = cq >> 1;
  int n = blockIdx.x * 16 + nl;
  float acc[8] = {0, 0, 0, 0, 0, 0, 0, 0};
  float ssum = 0.f;
  if (n < N) {
    int p0 = rp[n], p1 = rp[n + 1];
    float adv = ad[n * 2 + h];
    int p = p0 + half;
    // main: 4 independent csr->gather chains in flight per iteration
    for (; p + 12 < p1; p += 16) {
      int sA = csr[p], sB = csr[p + 4], sC = csr[p + 8], sD = csr[p + 12];
      float eA = as[sA * 2 + h] + adv;
      float eB = as[sB * 2 + h] + adv;
      float eC = as[sC * 2 + h] + adv;
      float eD = as[sD * 2 + h] + adv;
      uint4 uA = h1h[(size_t)sA * 4 + cq];
      uint4 uB = h1h[(size_t)sB * 4 + cq];
      uint4 uC = h1h[(size_t)sC * 4 + cq];
      uint4 uD = h1h[(size_t)sD * 4 + cq];
      float xA = __expf(lrelu(eA));
      float xB = __expf(lrelu(eB));
      float xC = __expf(lrelu(eC));
      float xD = __expf(lrelu(eD));
      ssum += (xA + xB) + (xC + xD);
      acc8(acc, xA, uA);
      acc8(acc, xB, uB);
      acc8(acc, xC, uC);
      acc8(acc, xD, uD);
    }
    // tail: <=3 edges, one parallel memory round (clamped + predicated)
    if (p < p1) {
      bool vB = p + 4 < p1, vC = p + 8 < p1;
      int pB = vB ? p + 4 : p;
      int pC = vC ? p + 8 : p;
      int sA = csr[p], sB = csr[pB], sC = csr[pC];
      float eA = as[sA * 2 + h] + adv;
      float eB = as[sB * 2 + h] + adv;
      float eC = as[sC * 2 + h] + adv;
      uint4 uA = h1h[(size_t)sA * 4 + cq];
      uint4 uB = h1h[(size_t)sB * 4 + cq];
      uint4 uC = h1h[(size_t)sC * 4 + cq];
      float xA = __expf(lrelu(eA));
      float xB = vB ? __expf(lrelu(eB)) : 0.f;
      float xC = vC ? __expf(lrelu(eC)) : 0.f;
      ssum += xA + xB + xC;
      acc8(acc, xA, uA);
      acc8(acc, xB, uB);
      acc8(acc, xC, uC);
    }
  }
  // combine 4 split-K halves (lanes r^4, r^8 within the 16-lane node group)
#pragma unroll
  for (int j = 0; j < 8; j++) acc[j] += __shfl_xor(acc[j], 4);
  ssum += __shfl_xor(ssum, 4);
#pragma unroll
  for (int j = 0; j < 8; j++) acc[j] += __shfl_xor(acc[j], 8);
  ssum += __shfl_xor(ssum, 8);
  if (n < N && half == 0) {
    float inv = 1.0f / (ssum + 1e-16f);
    float4 ba = ((const float4*)b1)[cq * 2];
    float4 bb = ((const float4*)b1)[cq * 2 + 1];
    float xv[8];
    xv[0] = fmaxf(fmaf(acc[0], inv, ba.x), 0.f);
    xv[1] = fmaxf(fmaf(acc[1], inv, ba.y), 0.f);
    xv[2] = fmaxf(fmaf(acc[2], inv, ba.z), 0.f);
    xv[3] = fmaxf(fmaf(acc[3], inv, ba.w), 0.f);
    xv[4] = fmaxf(fmaf(acc[4], inv, bb.x), 0.f);
    xv[5] = fmaxf(fmaf(acc[5], inv, bb.y), 0.f);
    xv[6] = fmaxf(fmaf(acc[6], inv, bb.z), 0.f);
    xv[7] = fmaxf(fmaf(acc[7], inv, bb.w), 0.f);
    uint4 u;
    u.x = (unsigned)f2h(xv[0]) | ((unsigned)f2h(xv[1]) << 16);
    u.y = (unsigned)f2h(xv[2]) | ((unsigned)f2h(xv[3]) << 16);
    u.z = (unsigned)f2h(xv[4]) | ((unsigned)f2h(xv[5]) << 16);
    u.w = (unsigned)f2h(xv[6]) | ((unsigned)f2h(xv[7]) << 16);
    x1h[(size_t)n * 4 + cq] = u;
    // attn2 scalars via 32-dots (channel slice cq*8..cq*8+7)
    int ch0 = cq * 8;
    float ss = 0.f, sd = 0.f;
#pragma unroll
    for (int j = 0; j < 8; j++) {
      ss = fmaf(xv[j], val[ch0 + j], ss);
      sd = fmaf(xv[j], vbl[ch0 + j], sd);
    }
    ss += __shfl_xor(ss, 1); sd += __shfl_xor(sd, 1);
    ss += __shfl_xor(ss, 2); sd += __shfl_xor(sd, 2);
    if (cq == 0) { as2[n] = ss; ad2[n] = sd; }
  }
}

// ------- fused softmax+agg over x1 (split-K=4, shfl) + node GEMM 32->40 -----
// block = 16 nodes x 16 threads; gather x1h rows (64B = ONE line per edge);
// epilogue: out[n] = W2^T * aggx[n] + b2 (per-node, LDS GEMM).
__global__ __launch_bounds__(256, 8) void agg2_gemm(
    const int* __restrict__ rp, const int* __restrict__ csr,
    const float* __restrict__ as, const float* __restrict__ ad,
    const uint4* __restrict__ x1h, const float* __restrict__ W2,
    const float* __restrict__ b2, float* __restrict__ outp, int N) {
  __shared__ float Wl[32 * 40];
  __shared__ float xt[16][33];
  __shared__ float hr[16][41];
  int t = threadIdx.x;
  for (int i = t; i < 320; i += 256)
    ((float4*)Wl)[i] = ((const float4*)W2)[i];
  int nl = t >> 4, r = t & 15;
  int half = r >> 2, cq = r & 3;
  int n = blockIdx.x * 16 + nl;
  float acc[8] = {0, 0, 0, 0, 0, 0, 0, 0};
  float ssum = 0.f;
  if (n < N) {
    int p0 = rp[n], p1 = rp[n + 1];
    float adv = ad[n];
    int p = p0 + half;
    for (; p + 12 < p1; p += 16) {
      int sA = csr[p], sB = csr[p + 4], sC = csr[p + 8], sD = csr[p + 12];
      float eA = as[sA] + adv;
      float eB = as[sB] + adv;
      float eC = as[sC] + adv;
      float eD = as[sD] + adv;
      uint4 uA = x1h[(size_t)sA * 4 + cq];
      uint4 uB = x1h[(size_t)sB * 4 + cq];
      uint4 uC = x1h[(size_t)sC * 4 + cq];
      uint4 uD = x1h[(size_t)sD * 4 + cq];
      float xA = __expf(lrelu(eA));
      float xB = __expf(lrelu(eB));
      float xC = __expf(lrelu(eC));
      float xD = __expf(lrelu(eD));
      ssum += (xA + xB) + (xC + xD);
      acc8(acc, xA, uA);
      acc8(acc, xB, uB);
      acc8(acc, xC, uC);
      acc8(acc, xD, uD);
    }
    if (p < p1) {
      bool vB = p + 4 < p1, vC = p + 8 < p1;
      int pB = vB ? p + 4 : p;
      int pC = vC ? p + 8 : p;
      int sA = csr[p], sB = csr[pB], sC = csr[pC];
      float eA = as[sA] + adv;
      float eB = as[sB] + adv;
      float eC = as[sC] + adv;
      uint4 uA = x1h[(size_t)sA * 4 + cq];
      uint4 uB = x1h[(size_t)sB * 4 + cq];
      uint4 uC = x1h[(size_t)sC * 4 + cq];
      float xA = __expf(lrelu(eA));
      float xB = vB ? __expf(lrelu(eB)) : 0.f;
      float xC = vC ? __expf(lrelu(eC)) : 0.f;
      ssum += xA + xB + xC;
      acc8(acc, xA, uA);
      acc8(acc, xB, uB);
      acc8(acc, xC, uC);
    }
  }
#pragma unroll
  for (int j = 0; j < 8; j++) acc[j] += __shfl_xor(acc[j], 4);
  ssum += __shfl_xor(ssum, 4);
#pragma unroll
  for (int j = 0; j < 8; j++) acc[j] += __shfl_xor(acc[j], 8);
  ssum += __shfl_xor(ssum, 8);
  if (n < N && half == 0) {
    float inv = 1.0f / (ssum + 1e-16f);
    int ch0 = cq * 8;
#pragma unroll
    for (int j = 0; j < 8; j++) xt[nl][ch0 + j] = acc[j] * inv;
  }
  __syncthreads();  // covers Wl load + xt writes
  if (n < N && r < 8) {
    float a2[5] = {0, 0, 0, 0, 0};
    int cb = r * 5;
    for (int k = 0; k < 32; k++) {
      float x = xt[nl][k];
#pragma unroll
      for (int c = 0; c < 5; c++)
        a2[c] = fmaf(x, Wl[k * 40 + cb + c], a2[c]);
    }
#pragma unroll
    for (int c = 0; c < 5; c++) hr[nl][cb + c] = a2[c];
  }
  __syncthreads();
  if (n < N && r < 10) {
    const float* s = hr[nl] + r * 4;
    float4 bb = ((const float4*)b2)[r];
    float4 v;
    v.x = s[0] + bb.x; v.y = s[1] + bb.y;
    v.z = s[2] + bb.z; v.w = s[3] + bb.w;
    ((float4*)outp)[(size_t)n * 10 + r] = v;
  }
}

// ---------------- host launcher ----------------
extern "C" void kernel_launch(void* const* d_in, const int* in_sizes, int n_in,
                              void* d_out, int out_size, void* d_ws, size_t ws_size,
                              hipStream_t stream) {
  const float* X    = (const float*)d_in[0];
  const long long* eg64 = (const long long*)d_in[1];
  const int* eg32   = (const int*)d_in[1];
  const float* W1   = (const float*)d_in[3];
  const float* as1w = (const float*)d_in[4];
  const float* ad1w = (const float*)d_in[5];
  const float* b1   = (const float*)d_in[6];
  const float* W2   = (const float*)d_in[7];
  const float* as2w = (const float*)d_in[8];
  const float* ad2w = (const float*)d_in[9];
  const float* b2   = (const float*)d_in[10];
  float* out = (float*)d_out;

  const int N  = in_sizes[0] / 128;
  const int E  = in_sizes[1] / 2;
  const int EN = E + N;
  const int NB2 = (N + CB_SZ - 1) / CB_SZ;
  const int NWG = (EN + SC_CHUNK - 1) / SC_CHUNK;

  char* wbase = (char*)d_ws;
  size_t off = 0;
  auto alloc = [&](size_t bytes) -> void* {
    void* p = wbase + off;
    off += (bytes + 255) & ~(size_t)255;
    return p;
  };

  uint4* h1h = (uint4*)alloc((size_t)N * 64);        // fp16 h1, 64B rows
  // tmp (CSR build scratch) and x1h (fp16 x1 payload) are temporally
  // disjoint: tmp dies at bucket_rp_sort, x1h is born at agg1_attn.
  size_t usz = (size_t)EN * 4;
  if ((size_t)N * 64 > usz) usz = (size_t)N * 64;
  char* uni = (char*)alloc(usz);
  uint4* x1h = (uint4*)uni;
  int*   tmp = (int*)uni;
  float* as1 = (float*)alloc((size_t)N * 2 * 4);
  float* ad1 = (float*)alloc((size_t)N * 2 * 4);
  float* as2 = (float*)alloc((size_t)N * 4);
  float* ad2 = (float*)alloc((size_t)N * 4);
  int* rp     = (int*)alloc((size_t)(N + 1) * 4);
  int* bhist  = (int*)alloc((NBMAX + 1) * 4);  // +1: bflag
  int* bscan  = (int*)alloc((NBMAX + 1) * 4);
  int* gcur   = (int*)alloc(NBMAX * 4);
  int* csr    = (int*)alloc((size_t)EN * 4);
  (void)ws_size; (void)n_in; (void)out_size;

  const int gN = (N + 127) / 128;

  // CSR build: hist+scan (last-block fused) -> scatter || gemm1f -> bucket sort
  hipMemsetAsync(bhist, 0, (NBMAX + 1) * 4, stream);
  bucket_hist_scan<<<1024, 256, 0, stream>>>(eg64, eg32, E, N, NB2,
                                             bhist, bhist + NBMAX, bscan, gcur);
  // dual-role: blocks [0,NWG) scatter edges; blocks [NWG,NWG+gN) run gemm1f
  scatter_gemm1<<<NWG + gN, 256, 0, stream>>>(eg64, eg32, E, N, NB2, NWG,
                                              gcur, tmp, X, W1, as1w, ad1w,
                                              h1h, as1, ad1);
  bucket_rp_sort<<<NB2, 256, 0, stream>>>(bscan, tmp, rp, csr, N, EN);

  // agg1 + x1 pack + attn2 dots (gemm2 folded out via linearity)
  agg1_attn<<<(N + 15) / 16, 256, 0, stream>>>(rp, csr, as1, ad1, h1h, b1,
                                               W2, as2w, ad2w, x1h, as2, ad2, N);
  // Layer 2: aggregate x1, then per-node GEMM 32->40 + bias -> output
  agg2_gemm<<<(N + 15) / 16, 256, 0, stream>>>(rp, csr, as2, ad2, x1h,
                                               W2, b2, out, N);
}